// Round 16
// baseline (145.345 us; speedup 1.0000x reference)
//
#include <hip/hip_runtime.h>
#include <math.h>

#define NSP 32768   // H*W*D = 32*32*32
#define NCH 64

typedef _Float16 half8 __attribute__((ext_vector_type(8)));
typedef _Float16 half4 __attribute__((ext_vector_type(4)));
typedef _Float16 half2v __attribute__((ext_vector_type(2)));
typedef float f32x4 __attribute__((ext_vector_type(4)));

// ---------------------------------------------------------------------------
// K1 (MFMA): U = gelu(proj1_w @ x^T + b)   (U layout: f16 [C][N])
__global__ __launch_bounds__(256) void k_proj1m(const float* __restrict__ x,
        const half8* __restrict__ Wp1, const float* __restrict__ b,
        _Float16* __restrict__ Uh) {
    __shared__ __align__(16) _Float16 Sx[64 * 72];   // 9216 B
    int t = threadIdx.x;
    int n0 = blockIdx.x * 64;
    int lane = t & 63, wv = t >> 6;
    for (int i = wv; i < 64; i += 4) {
        float v = x[(size_t)(n0 + i) * 64 + lane];
        Sx[i * 72 + lane] = (_Float16)v;
    }
    __syncthreads();
    int pl = lane & 15, g = lane >> 4;
    int ob = wv;
    const half8* wbase = Wp1 + ob * 64 + lane;       // +256 per kb
    #pragma unroll
    for (int nt = 0; nt < 4; ++nt) {
        f32x4 acc4 = {0.f, 0.f, 0.f, 0.f};
        const _Float16* sb = &Sx[(nt * 16 + pl) * 72 + g * 8];
        #pragma unroll
        for (int kb = 0; kb < 2; ++kb) {
            half8 af = wbase[kb * 256];
            half8 bf = *(const half8*)(sb + kb * 32);
            acc4 = __builtin_amdgcn_mfma_f32_16x16x32_f16(af, bf, acc4, 0, 0, 0);
        }
        int n = n0 + nt * 16 + pl;
        #pragma unroll
        for (int r = 0; r < 4; ++r) {
            int o = ob * 16 + g * 4 + r;
            float a = acc4[r] + b[o];
            float gv = 0.5f * a * (1.0f + erff(a * 0.70710678118654752f));
            Uh[(size_t)o * NSP + n] = (_Float16)gv;
        }
    }
}

// ---------------------------------------------------------------------------
// K2: depthwise 5x5x5, pad 2.  f16 in/out; weights uniform->SGPR.
__global__ __launch_bounds__(256) void k_dw5(const _Float16* __restrict__ in,
        const float* __restrict__ w, const float* __restrict__ b,
        _Float16* __restrict__ out) {
    __shared__ float Sb5[2][20 * 38];                // 6080 B
    int t = threadIdx.x;
    int bid = blockIdx.x;
    int blk = (bid & 7) * 128 + (bid >> 3);          // XCD-chunked
    int c  = blk >> 4;
    int hq = (blk >> 1) & 7;
    int wq = blk & 1;
    int d  = t & 31;
    int wbloc = t >> 5;                              // 0..7
    int wb = wq * 8 + wbloc;
    const float* wc = w + c * 125;                   // uniform -> scalar loads
    const _Float16* src = in + ((size_t)c << 15);

    for (int idx = t; idx < 160; idx += 256) {
        int bi = idx / 80, r = idx % 80;
        int wi = r >> 2, e = r & 3;
        int Dp = (e < 2) ? e : 32 + e;               // {0,1,34,35}
        Sb5[bi][wi * 38 + Dp] = 0.f;
    }

    float bc = b[c];
    float acc[4][2];
    #pragma unroll
    for (int a = 0; a < 4; ++a) { acc[a][0] = bc; acc[a][1] = bc; }

    #define STAGE5(m)                                                        \
        { int hh_ = 4 * hq + (m) - 2;                                        \
          if ((unsigned)hh_ < 32u) {                                         \
            const _Float16* row_ = src + (hh_ << 10);                        \
            for (int idx = t; idx < 80; idx += 256) {                        \
                int wi = idx >> 2, oct = idx & 3;                            \
                int wj = 16 * wq - 2 + wi;                                   \
                half8 vv = (half8)(_Float16)0.f;                             \
                if ((unsigned)wj < 32u)                                      \
                    vv = *(const half8*)&row_[(wj << 5) + oct * 8];          \
                float* dst = &Sb5[(m) & 1][wi * 38 + 2 + oct * 8];           \
                dst[0] = (float)vv[0]; dst[1] = (float)vv[1];                \
                dst[2] = (float)vv[2]; dst[3] = (float)vv[3];                \
                dst[4] = (float)vv[4]; dst[5] = (float)vv[5];                \
                dst[6] = (float)vv[6]; dst[7] = (float)vv[7];                \
            } } }

    STAGE5(0)
    __syncthreads();
    #pragma unroll 1
    for (int m = 0; m < 8; ++m) {
        if (m < 7) STAGE5(m + 1)
        int hh = 4 * hq + m - 2;
        if ((unsigned)hh < 32u) {
            float v[6][5];
            const float* sb = &Sb5[m & 1][0];
            #pragma unroll
            for (int jc = 0; jc < 6; ++jc)
                #pragma unroll
                for (int l = 0; l < 5; ++l)
                    v[jc][l] = sb[(2 * wbloc + jc) * 38 + d + l];
            #pragma unroll
            for (int a = 0; a < 4; ++a) {
                if (a <= m && m <= a + 4) {
                    const float* wr = wc + (m - a) * 25;   // uniform
                    float s0 = 0.f, s1 = 0.f;
                    #pragma unroll
                    for (int j = 0; j < 5; ++j)
                        #pragma unroll
                        for (int l = 0; l < 5; ++l) {
                            float wv2 = wr[j * 5 + l];
                            s0 += wv2 * v[j][l];
                            s1 += wv2 * v[j + 1][l];
                        }
                    acc[a][0] += s0;
                    acc[a][1] += s1;
                }
            }
        }
        __syncthreads();
    }
    #pragma unroll
    for (int a = 0; a < 4; ++a)
        #pragma unroll
        for (int bb = 0; bb < 2; ++bb)
            out[(size_t)c * NSP + ((4 * hq + a) << 10) + ((2 * wb + bb) << 5) + d]
                = (_Float16)acc[a][bb];
    #undef STAGE5
}

// ---------------------------------------------------------------------------
// K3: depthwise 7x7x7 dilation 3.  f16 in/out; half8 staging; pk inner.
__global__ __launch_bounds__(256) void k_dw7(const _Float16* __restrict__ in,
        const float* __restrict__ w, const float* __restrict__ b,
        _Float16* __restrict__ out) {
    __shared__ float Sb7[2][26 * 52];                // 10816 B
    int t = threadIdx.x;
    int bid = blockIdx.x;
    int blk = (bid & 7) * 96 + (bid >> 3);           // XCD-chunked
    int c  = blk / 12;
    int h0 = (blk % 12) >> 2;
    int wq = blk & 3;
    int d  = t & 31;
    int wloc = t >> 5;                               // 0..7
    int w_ = wq * 8 + wloc;
    const float* wc = w + c * 343;                   // uniform -> scalar loads
    const _Float16* src = in + ((size_t)c << 15);

    for (int idx = t; idx < 936; idx += 256) {
        int bi = idx / 468, r = idx % 468;
        int wi = r / 18, e = r % 18;
        int Dp = (e < 9) ? e : 32 + e;               // {0..8, 41..49}
        Sb7[bi][wi * 52 + Dp] = 0.f;
    }

    float bc = b[c];
    float acc[11];
    #pragma unroll
    for (int a = 0; a < 11; ++a) acc[a] = bc;

    #define STAGE7(m)                                                        \
        { int hh_ = h0 + 3 * (m) - 9;                                        \
          if ((unsigned)hh_ < 32u) {                                         \
            const _Float16* row_ = src + (hh_ << 10);                        \
            for (int idx = t; idx < 104; idx += 256) {                       \
                int wi = idx >> 2, oct = idx & 3;                            \
                int wj = 8 * wq - 9 + wi;                                    \
                half8 vv = (half8)(_Float16)0.f;                             \
                if ((unsigned)wj < 32u)                                      \
                    vv = *(const half8*)&row_[(wj << 5) + oct * 8];          \
                float* dst = &Sb7[(m) & 1][wi * 52 + 9 + oct * 8];           \
                dst[0] = (float)vv[0]; dst[1] = (float)vv[1];                \
                dst[2] = (float)vv[2]; dst[3] = (float)vv[3];                \
                dst[4] = (float)vv[4]; dst[5] = (float)vv[5];                \
                dst[6] = (float)vv[6]; dst[7] = (float)vv[7];                \
            } } }

    STAGE7(0)
    __syncthreads();
    #pragma unroll 1
    for (int m = 0; m < 17; ++m) {
        if (m < 16) STAGE7(m + 1)
        int hh = h0 + 3 * m - 9;
        if ((unsigned)hh < 32u) {
            float vf[49];
            const float* sb = &Sb7[m & 1][0];
            #pragma unroll
            for (int jw = 0; jw < 7; ++jw)
                #pragma unroll
                for (int l = 0; l < 7; ++l)
                    vf[jw * 7 + l] = sb[(wloc + 3 * jw) * 52 + d + 3 * l];
            #pragma unroll
            for (int a = 0; a < 11; ++a) {
                if (a <= m && m <= a + 6) {
                    const float* wr = wc + (m - a) * 49;   // uniform
                    float sA = 0.f, sB = 0.f;              // 2 chains -> pk
                    #pragma unroll
                    for (int q = 0; q < 24; ++q) {
                        sA = fmaf(wr[2 * q],     vf[2 * q],     sA);
                        sB = fmaf(wr[2 * q + 1], vf[2 * q + 1], sB);
                    }
                    acc[a] += sA + sB + wr[48] * vf[48];
                }
            }
        }
        __syncthreads();
    }
    #pragma unroll
    for (int a = 0; a < 11; ++a) {
        int h = h0 + 3 * a;
        if (h < 32)
            out[(size_t)c * NSP + (h << 10) + (w_ << 5) + d] = (_Float16)acc[a];
    }
    #undef STAGE7
}

// ---------------------------------------------------------------------------
// K4: transpose f16 [C][N] -> f16 [N][C], half8 both sides
__global__ __launch_bounds__(256) void k_tr(const _Float16* __restrict__ in,
        _Float16* __restrict__ outh) {
    __shared__ __align__(16) _Float16 tile[64 * 74];  // 9472 B
    int t = threadIdx.x;
    int n0 = blockIdx.x * 64;
    #pragma unroll
    for (int i = 0; i < 2; ++i) {
        int u = i * 256 + t;         // 0..511
        int c = u >> 3, oct = u & 7;
        half8 v = *(const half8*)&in[(size_t)c * NSP + n0 + oct * 8];
        *(half8*)&tile[c * 74 + oct * 8] = v;
    }
    __syncthreads();
    #pragma unroll
    for (int i = 0; i < 2; ++i) {
        int u = i * 256 + t;
        int nl = u >> 3, co = u & 7;
        half8 r;
        #pragma unroll
        for (int j = 0; j < 8; ++j) r[j] = tile[(co * 8 + j) * 74 + nl];
        *(half8*)&outh[(size_t)(n0 + nl) * 64 + co * 8] = r;
    }
}

// ---------------------------------------------------------------------------
// K5 (fused): ALL weight packs in one kernel.
__global__ __launch_bounds__(256) void k_wpack_all(
        const float* __restrict__ p1w, const float* __restrict__ c1w,
        const float* __restrict__ p2w, const float* __restrict__ dcw,
        const float* __restrict__ ofw,
        _Float16* __restrict__ Wp1, _Float16* __restrict__ Wc1,
        _Float16* __restrict__ Wp2f, _Float16* __restrict__ Wp,
        _Float16* __restrict__ Wp2) {
    int bidx = blockIdx.x;
    int t = threadIdx.x;
    if (bidx < 48) {
        const float* w = (bidx < 16) ? p1w : (bidx < 32) ? c1w : p2w;
        _Float16* Wd   = (bidx < 16) ? Wp1 : (bidx < 32) ? Wc1 : Wp2f;
        int idx = (bidx & 15) * 256 + t;             // 0..4095
        int j = idx & 7;
        int l = (idx >> 3) & 63;
        int obk = idx >> 9;
        int ob = obk & 3, kb = obk >> 2;
        int o = ob * 16 + (l & 15);
        int Kp = kb * 32 + (l >> 4) * 8 + j;
        Wd[idx] = (_Float16)w[o * 64 + Kp];
    } else if (bidx < 480) {
        int idx = (bidx - 48) * 256 + t;             // 0..110591
        int j = idx & 7;
        int l = (idx >> 3) & 63;
        int obk = idx >> 9;
        int ob = obk & 3, kb = obk >> 2;
        int o = ob * 16 + (l & 15);
        int Kp = kb * 32 + (l >> 4) * 8 + j;
        int k = Kp >> 6, c = Kp & 63;
        Wp[idx] = (_Float16)dcw[(size_t)o * 1728 + c * 27 + k];
    } else {
        int idx = (bidx - 480) * 256 + t;            // 0..165887
        int j = idx & 7;
        int l = (idx >> 3) & 63;
        int obk = idx >> 9;                          // 0..323
        int ob = obk % 6, kb = obk / 6;
        int o = ob * 16 + (l & 15);
        int Kp = kb * 32 + (l >> 4) * 8 + j;
        int k = Kp >> 6, c = Kp & 63;
        Wp2[idx] = (o < 81) ? (_Float16)ofw[(size_t)o * 1728 + c * 27 + k]
                            : (_Float16)0.f;
    }
}

// ---------------------------------------------------------------------------
// K5c: offset conv, 32-position tile, kh-chunked dbuf halo.  Output OFFn f16
// [N][108] (slot = k*4 + comp) via LDS-transpose epilogue (aliased).
__global__ __launch_bounds__(384) void k_offg(const _Float16* __restrict__ aTh,
        const half8* __restrict__ Wp2, const float* __restrict__ obias,
        _Float16* __restrict__ OFFn) {
    __shared__ __align__(16) char SMEM[29376];       // S2 | TFh alias
    _Float16* S2  = (_Float16*)SMEM;                 // [2][3*34*72]
    _Float16* TFh = (_Float16*)SMEM;                 // [32][108]
    const int SB = 3 * 34 * 72;                      // 7344 halfs per buffer
    int t = threadIdx.x;
    int bid = blockIdx.x;
    int blk = (bid & 7) * 128 + (bid >> 3);          // 1024 blocks, XCD-chunked
    int h = blk >> 5, w = blk & 31;
    int n0 = blk << 5;
    int lane = t & 63, wv = t >> 6;                  // wv 0..5
    int co8 = (lane & 7) << 3;

    for (int u = t; u < 864; u += 384) {             // zero d-edge rows
        int bi = u / 432, r2 = u % 432;
        int nbw = r2 / 144, r3 = r2 % 144;
        int dd = (r3 >= 72) ? 33 : 0, cc = r3 % 72;
        S2[bi * SB + (nbw * 34 + dd) * 72 + cc] = (_Float16)0.f;
    }

    int pl = lane & 15, g = lane >> 4;
    int obi = wv;
    f32x4 acc[2];
    acc[0] = (f32x4){0.f, 0.f, 0.f, 0.f};
    acc[1] = (f32x4){0.f, 0.f, 0.f, 0.f};
    const half8* wb = Wp2 + obi * 64 + lane;

    #define OSTAGE(kh)                                                        \
        { int hh_ = h + (kh) - 1;                                            \
          bool okh_ = (unsigned)hh_ < 32u;                                   \
          for (int u = wv; u < 12; u += 6) {                                 \
              int nbw = u >> 2, oct = u & 3;                                 \
              int wj = w + nbw - 1;                                          \
              int di = oct * 8 + (lane >> 3);                                \
              bool ok = okh_ & ((unsigned)wj < 32u);                         \
              half8 vv = (half8)(_Float16)0.f;                               \
              if (ok) vv = *(const half8*)(aTh +                             \
                  ((size_t)((((hh_ << 5) + wj) << 5) + di)) * 64 + co8);     \
              *(half8*)&S2[((kh) & 1) * SB + (nbw * 34 + 1 + di) * 72 + co8] \
                  = vv;                                                      \
          } }

    #define OCOMP(kh)                                                        \
        { const _Float16* sb = &S2[((kh) & 1) * SB + pl * 72 + g * 8];       \
          _Pragma("unroll")                                                  \
          for (int kk = 0; kk < 18; ++kk) {                                  \
              int kglob = (kh) * 9 + (kk >> 1);                              \
              int kw3 = (kglob / 3) % 3, kd = kglob % 3;                     \
              half8 af = wb[(size_t)((kh) * 18 + kk) * 384];                 \
              _Pragma("unroll")                                              \
              for (int pt = 0; pt < 2; ++pt) {                               \
                  int row = kw3 * 34 + pt * 16 + kd;                         \
                  half8 bf = *(const half8*)(sb + row * 72 + (kk & 1) * 32); \
                  acc[pt] = __builtin_amdgcn_mfma_f32_16x16x32_f16(          \
                                af, bf, acc[pt], 0, 0, 0);                   \
              }                                                              \
          } }

    OSTAGE(0)
    __syncthreads();
    OSTAGE(1)
    OCOMP(0)
    __syncthreads();
    OSTAGE(2)
    OCOMP(1)
    __syncthreads();
    OCOMP(2)
    #undef OSTAGE
    #undef OCOMP

    __syncthreads();                                 // S2 -> TFh alias switch
    #pragma unroll
    for (int pt = 0; pt < 2; ++pt) {
        int pos = pt * 16 + pl;
        #pragma unroll
        for (int r = 0; r < 4; ++r) {
            int o = obi * 16 + g * 4 + r;
            if (o < 81) {
                int slot = (o / 3) * 4 + o % 3;
                TFh[pos * 108 + slot] = (_Float16)(acc[pt][r] + obias[o]);
            }
        }
    }
    __syncthreads();
    for (int u = t; u < 864; u += 384) {             // 32 rows x 27 half4
        int row = u / 27, q = u - row * 27;
        half4 v = *(const half4*)&TFh[row * 108 + q * 4];
        *(half4*)&OFFn[(size_t)(n0 + row) * 108 + q * 4] = v;
    }
}

// ---------------------------------------------------------------------------
// K6 (new): deformable gather via LDS halo + MFMA GEMM.
// Block = 32 positions (one d-row).  18 chunks = 9 (kh,kw) x 2 ch-halves.
// Per chunk: stage HALO[9 hw][36 d][32ch+4pad] (coalesced, 20.25 instrs),
// then gather corners from LDS (ds_read_b128; out-of-volume reads staged
// zeros so no mask needed), MFMA 3 kb per chunk; stage(c+1) || MFMA(c).
// Rare |off|>=1 taps (far flag in TPF[3]) take the old global path.
__global__ __launch_bounds__(256) void k_deform(const _Float16* __restrict__ aTh,
        const _Float16* __restrict__ OFFn, const half8* __restrict__ Wp,
        const float* __restrict__ db, _Float16* __restrict__ dcnT) {
    __shared__ __align__(16) _Float16 HALO[9 * 36 * 36];  // 23328 B
    __shared__ __align__(16) _Float16 S[32 * 104];        // 6656 B
    __shared__ __align__(16) _Float16 TPF[864 * 4];       // 6912 B {rh,rw,rd,lf}
    __shared__ int TPv[864];                              // 3456 B (40352 B)
    int t = threadIdx.x;
    int bid = blockIdx.x;
    int blk = (bid & 7) * 128 + (bid >> 3);  // 1024 blocks, XCD-chunked
    int n0 = blk * 32;
    int h = blk >> 5, w = blk & 31;
    int lane = t & 63, wv = t >> 6;

    for (int idx = t; idx < 864; idx += 256) {        // Phase A: 27k x 32p
        int p = idx & 31, k = idx >> 5;
        int n = n0 + p;
        int kh = k / 9 - 1, kw = (k / 3) % 3 - 1, kd = k % 3 - 1;
        half4 ov4 = *(const half4*)&OFFn[(size_t)n * 108 + k * 4];
        float ph = (float)(h + kh) + (float)ov4[0];
        float pw = (float)(w + kw) + (float)ov4[1];
        float pd = (float)(p + kd) + (float)ov4[2];
        float fh = floorf(ph), fw = floorf(pw), fd = floorf(pd);
        int ih = (int)fh, iw = (int)fw, id = (int)fd;
        int nb0 = ih * 1024 + iw * 32 + id;
        int rh0 = ih - h - kh + 1;                    // {0,1} if near
        int rw0 = iw - w - kw + 1;
        int rd0 = id - p - kd + 1;
        bool far = ((unsigned)rh0 > 1u) | ((unsigned)rw0 > 1u)
                 | ((unsigned)rd0 > 1u);
        int lf = far ? 255 : ((rh0 << 7) | (rw0 << 6) | (id + 2));
        int mask = 0;
        #pragma unroll
        for (int cb = 0; cb < 8; ++cb) {
            int hh = ih + ((cb >> 2) & 1);
            int wq = iw + ((cb >> 1) & 1);
            int dq = id + (cb & 1);
            bool ok = ((unsigned)hh < 32u) & ((unsigned)wq < 32u) & ((unsigned)dq < 32u);
            mask |= (ok ? 1 : 0) << cb;
        }
        TPv[idx] = ((nb0 + 4096) << 8) | mask;
        half4 f;
        f[0] = (_Float16)(ph - fh);
        f[1] = (_Float16)(pw - fw);
        f[2] = (_Float16)(pd - fd);
        f[3] = (_Float16)(float)lf;                   // <=255 exact in f16
        *(half4*)&TPF[idx * 4] = f;
    }
    __syncthreads();

    int p16 = lane >> 2, co = lane & 3;               // gather lane mapping
    int pl = lane & 15, g = lane >> 4;
    f32x4 acc[2];
    acc[0] = (f32x4){0.f, 0.f, 0.f, 0.f};
    acc[1] = (f32x4){0.f, 0.f, 0.f, 0.f};
    const half8* wbase = Wp + wv * 64 + lane;
    const _Float16* sbase0 = &S[pl * 104 + g * 8];
    const _Float16* sbase1 = &S[(16 + pl) * 104 + g * 8];

    // stage halo for chunk cc: 9 hw-rows x 36 dd x 32 ch (half of channels)
    #define DSTAGE(cc)                                                       \
        { int khkw_ = (cc) >> 1, cb_ = (cc) & 1;                             \
          int kh_ = khkw_ / 3 - 1, kw_ = khkw_ % 3 - 1;                      \
          int bh_ = h + kh_ - 1, bw_ = w + kw_ - 1;                          \
          for (int i = t; i < 1296; i += 256) {                              \
              int r_ = i / 144;                                              \
              int rem_ = i - r_ * 144;                                       \
              int dd_ = rem_ >> 2, c4_ = rem_ & 3;                           \
              int hh_ = bh_ + r_ / 3;                                        \
              int ww_ = bw_ + r_ % 3;                                        \
              int dq_ = dd_ - 2;                                             \
              bool ok_ = ((unsigned)hh_ < 32u) & ((unsigned)ww_ < 32u)       \
                       & ((unsigned)dq_ < 32u);                              \
              half8 vv_ = (half8)(_Float16)0.f;                              \
              if (ok_) vv_ = *(const half8*)&aTh[                            \
                  (size_t)(((hh_ << 5) + ww_) * 32 + dq_) * 64               \
                  + cb_ * 32 + c4_ * 8];                                     \
              *(half8*)&HALO[(r_ * 36 + dd_) * 36 + c4_ * 8] = vv_;          \
          } }

    // gather chunk cc into S (3 taps x 32 pos x 32 ch)
    #define DGATHER(cc)                                                      \
        { int khkw_ = (cc) >> 1, cb_ = (cc) & 1;                             \
          for (int u = wv; u < 6; u += 4) {                                  \
              int kd_ = u >> 1, pgh_ = u & 1;                                \
              int p_ = pgh_ * 16 + p16;                                      \
              int tap = (khkw_ * 3 + kd_) * 32 + p_;                         \
              int v_ = TPv[tap];                                             \
              int nb_ = (v_ >> 8) - 4096, mask_ = v_ & 255;                  \
              half4 f_ = *(const half4*)&TPF[tap * 4];                      \
              int lf_ = (int)(float)f_[3];                                   \
              _Float16 one_ = (_Float16)1.f;                                 \
              _Float16 rh_ = f_[0], rw_ = f_[1], rd_ = f_[2];                \
              _Float16 h0_ = one_ - rh_, w0_ = one_ - rw_, d0_ = one_ - rd_; \
              _Float16 t00_ = h0_ * w0_, t01_ = h0_ * rw_;                   \
              _Float16 t10_ = rh_ * w0_, t11_ = rh_ * rw_;                   \
              half2v a0_ = (half2v)0, a1_ = (half2v)0, a2_ = (half2v)0,      \
                     a3_ = (half2v)0;                                        \
              if (lf_ != 255) {                                              \
                  int rh0_ = (lf_ >> 7) & 1, rw0_ = (lf_ >> 6) & 1;          \
                  int idl_ = lf_ & 63;                                       \
                  _Pragma("unroll")                                          \
                  for (int i = 0; i < 8; ++i) {                              \
                      int r_ = (rh0_ + ((i >> 2) & 1)) * 3                   \
                             + (rw0_ + ((i >> 1) & 1));                      \
                      int dd_ = idl_ + (i & 1);                              \
                      half8 vv_ = *(const half8*)&HALO[                      \
                          (r_ * 36 + dd_) * 36 + co * 8];                    \
                      _Float16 txy_ = (i & 4) ? ((i & 2) ? t11_ : t10_)      \
                                             : ((i & 2) ? t01_ : t00_);      \
                      _Float16 wg_ = txy_ * ((i & 1) ? rd_ : d0_);           \
                      half2v wg2_ = {wg_, wg_};                              \
                      a0_ += (half2v){vv_[0], vv_[1]} * wg2_;                \
                      a1_ += (half2v){vv_[2], vv_[3]} * wg2_;                \
                      a2_ += (half2v){vv_[4], vv_[5]} * wg2_;                \
                      a3_ += (half2v){vv_[6], vv_[7]} * wg2_;                \
                  }                                                          \
              } else {                                                       \
                  int snb_ = nb_ < 0 ? 0 : (nb_ > 32767 ? 32767 : nb_);      \
                  _Pragma("unroll")                                          \
                  for (int i = 0; i < 8; ++i) {                              \
                      int nn_ = nb_ + ((i >> 2) & 1) * 1024                  \
                              + ((i >> 1) & 1) * 32 + (i & 1);               \
                      bool okc_ = (mask_ >> i) & 1;                          \
                      size_t ad_ = (size_t)(okc_ ? nn_ : snb_) << 6;         \
                      half8 vv_ = *(const half8*)(aTh + ad_ + cb_ * 32       \
                                                  + co * 8);                 \
                      _Float16 txy_ = (i & 4) ? ((i & 2) ? t11_ : t10_)      \
                                             : ((i & 2) ? t01_ : t00_);      \
                      _Float16 wg_ = txy_ * ((i & 1) ? rd_ : d0_);           \
                      wg_ = okc_ ? wg_ : (_Float16)0.f;                      \
                      half2v wg2_ = {wg_, wg_};                              \
                      a0_ += (half2v){vv_[0], vv_[1]} * wg2_;                \
                      a1_ += (half2v){vv_[2], vv_[3]} * wg2_;                \
                      a2_ += (half2v){vv_[4], vv_[5]} * wg2_;                \
                      a3_ += (half2v){vv_[6], vv_[7]} * wg2_;                \
                  }                                                          \
              }                                                              \
              half8 r8_;                                                     \
              r8_[0] = a0_[0]; r8_[1] = a0_[1]; r8_[2] = a1_[0];             \
              r8_[3] = a1_[1]; r8_[4] = a2_[0]; r8_[5] = a2_[1];             \
              r8_[6] = a3_[0]; r8_[7] = a3_[1];                              \
              *(half8*)&S[p_ * 104 + kd_ * 32 + co * 8] = r8_;               \
          } }

    // MFMA chunk cc: 3 kb's (kb = (khkw*3+kd)*2 + cb)
    #define DMFMA(cc)                                                        \
        { int khkw_ = (cc) >> 1, cb_ = (cc) & 1;                             \
          _Pragma("unroll")                                                  \
          for (int kd_ = 0; kd_ < 3; ++kd_) {                                \
              int kbg_ = (khkw_ * 3 + kd_) * 2 + cb_;                        \
              half8 af_ = wbase[(size_t)kbg_ * 256];                         \
              half8 bf0_ = *(const half8*)(sbase0 + kd_ * 32);               \
              half8 bf1_ = *(const half8*)(sbase1 + kd_ * 32);               \
              acc[0] = __builtin_amdgcn_mfma_f32_16x16x32_f16(af_, bf0_,     \
                           acc[0], 0, 0, 0);                                 \
              acc[1] = __builtin_amdgcn_mfma_f32_16x16x32_f16(af_, bf1_,     \
                           acc[1], 0, 0, 0);                                 \
          } }

    DSTAGE(0)
    __syncthreads();
    #pragma unroll 1
    for (int cc = 0; cc < 18; ++cc) {
        DGATHER(cc)
        __syncthreads();
        if (cc < 17) DSTAGE(cc + 1)
        DMFMA(cc)
        __syncthreads();
    }
    #undef DSTAGE
    #undef DGATHER
    #undef DMFMA

    #pragma unroll
    for (int pt = 0; pt < 2; ++pt) {
        half4 hv;
        #pragma unroll
        for (int r2 = 0; r2 < 4; ++r2) {
            int o = wv * 16 + g * 4 + r2;
            hv[r2] = (_Float16)(acc[pt][r2] + db[o]);
        }
        *(half4*)&dcnT[(size_t)(n0 + pt * 16 + pl) * 64 + wv * 16 + g * 4] = hv;
    }
}

// ---------------------------------------------------------------------------
// K7 (MFMA): a2 = conv1_w @ dcn + b ; h = U * a2 ; out = proj2_w @ h + b2 + x
__global__ __launch_bounds__(256) void k_finalm(const _Float16* __restrict__ dcnT,
        const _Float16* __restrict__ Uh, const float* __restrict__ x,
        const half8* __restrict__ Wc1, const float* __restrict__ c1b,
        const half8* __restrict__ Wp2f, const float* __restrict__ p2b,
        float* __restrict__ out) {
    __shared__ __align__(16) _Float16 Sd[64 * 72];   // 9216 B
    __shared__ __align__(16) _Float16 Sh[64 * 72];   // 9216 B
    int t = threadIdx.x;
    int n0 = blockIdx.x * 64;
    int lane = t & 63, wv = t >> 6;
    #pragma unroll
    for (int i = 0; i < 2; ++i) {
        int u = i * 256 + t;
        int nl = u >> 3, oct = u & 7;
        *(half8*)&Sd[nl * 72 + oct * 8] =
            *(const half8*)&dcnT[(size_t)(n0 + nl) * 64 + oct * 8];
    }
    __syncthreads();

    int pl = lane & 15, g = lane >> 4;
    int ob = wv;
    const half8* w1 = Wc1 + ob * 64 + lane;
    #pragma unroll
    for (int nt = 0; nt < 4; ++nt) {                 // GEMM1 + gate
        f32x4 acc4 = {0.f, 0.f, 0.f, 0.f};
        const _Float16* sb = &Sd[(nt * 16 + pl) * 72 + g * 8];
        #pragma unroll
        for (int kb = 0; kb < 2; ++kb) {
            half8 af = w1[kb * 256];
            half8 bf = *(const half8*)(sb + kb * 32);
            acc4 = __builtin_amdgcn_mfma_f32_16x16x32_f16(af, bf, acc4, 0, 0, 0);
        }
        int n = n0 + nt * 16 + pl;
        int o0 = ob * 16 + g * 4;
        float4 bb = *(const float4*)&c1b[o0];
        half4 hv;
        hv[0] = (_Float16)((float)Uh[(size_t)(o0 + 0) * NSP + n] * (acc4[0] + bb.x));
        hv[1] = (_Float16)((float)Uh[(size_t)(o0 + 1) * NSP + n] * (acc4[1] + bb.y));
        hv[2] = (_Float16)((float)Uh[(size_t)(o0 + 2) * NSP + n] * (acc4[2] + bb.z));
        hv[3] = (_Float16)((float)Uh[(size_t)(o0 + 3) * NSP + n] * (acc4[3] + bb.w));
        *(half4*)&Sh[(nt * 16 + pl) * 72 + o0] = hv;
    }
    __syncthreads();

    const half8* w2 = Wp2f + ob * 64 + lane;
    #pragma unroll
    for (int nt = 0; nt < 4; ++nt) {                 // GEMM2 + residual
        f32x4 acc4 = {0.f, 0.f, 0.f, 0.f};
        const _Float16* sb = &Sh[(nt * 16 + pl) * 72 + g * 8];
        #pragma unroll
        for (int kb = 0; kb < 2; ++kb) {
            half8 af = w2[kb * 256];
            half8 bf = *(const half8*)(sb + kb * 32);
            acc4 = __builtin_amdgcn_mfma_f32_16x16x32_f16(af, bf, acc4, 0, 0, 0);
        }
        int n = n0 + nt * 16 + pl;
        int o0 = ob * 16 + g * 4;
        float4 bb = *(const float4*)&p2b[o0];
        float4 xr = *(const float4*)&x[(size_t)n * 64 + o0];
        float4 ov;
        ov.x = acc4[0] + bb.x + xr.x;
        ov.y = acc4[1] + bb.y + xr.y;
        ov.z = acc4[2] + bb.z + xr.z;
        ov.w = acc4[3] + bb.w + xr.w;
        *(float4*)&out[(size_t)n * 64 + o0] = ov;
    }
}

// ---------------------------------------------------------------------------
extern "C" void kernel_launch(void* const* d_in, const int* in_sizes, int n_in,
                              void* d_out, int out_size, void* d_ws, size_t ws_size,
                              hipStream_t stream) {
    const float* x   = (const float*)d_in[0];
    const float* p1w = (const float*)d_in[1];
    const float* p1b = (const float*)d_in[2];
    const float* c0w = (const float*)d_in[3];
    const float* c0b = (const float*)d_in[4];
    const float* csw = (const float*)d_in[5];
    const float* csb = (const float*)d_in[6];
    const float* ofw = (const float*)d_in[7];
    const float* ofb = (const float*)d_in[8];
    const float* dcw = (const float*)d_in[9];
    const float* dcb = (const float*)d_in[10];
    const float* c1w = (const float*)d_in[11];
    const float* c1b = (const float*)d_in[12];
    const float* p2w = (const float*)d_in[13];
    const float* p2b = (const float*)d_in[14];
    float* out = (float*)d_out;

    char* ws = (char*)d_ws;
    const size_t CN2 = (size_t)NCH * NSP * 2;       // 4 MiB per [C][N] f16
    _Float16* Uh   = (_Float16*)(ws);
    _Float16* T0h  = (_Float16*)(ws + CN2);
    _Float16* T1h  = (_Float16*)(ws + 2 * CN2);
    _Float16* aTh  = (_Float16*)(ws + 3 * CN2);
    _Float16* OFFn = (_Float16*)(ws + 4 * CN2);     // [N][108] f16 = 7.08 MB
    _Float16* dcnT = (_Float16*)(ws + 4 * CN2 + (size_t)NSP * 108 * 2);
    _Float16* Wp   = dcnT + (size_t)NSP * 64;
    _Float16* Wp2  = Wp + 110592;
    _Float16* Wp1  = Wp2 + 165888;
    _Float16* Wc1  = Wp1 + 4096;
    _Float16* Wp2f = Wc1 + 4096;

    k_wpack_all<<<1128, 256, 0, stream>>>(p1w, c1w, p2w, dcw, ofw,
                                          Wp1, Wc1, Wp2f, Wp, Wp2);
    k_proj1m   <<<NSP / 64, 256, 0, stream>>>(x, (const half8*)Wp1, p1b, Uh);
    k_dw5      <<<1024, 256, 0, stream>>>(Uh, c0w, c0b, T0h);
    k_dw7      <<<768, 256, 0, stream>>>(T0h, csw, csb, T1h);
    k_tr       <<<NSP / 64, 256, 0, stream>>>(T1h, aTh);
    k_offg     <<<1024, 384, 0, stream>>>(aTh, (const half8*)Wp2, ofb, OFFn);
    k_deform   <<<1024, 256, 0, stream>>>(aTh, OFFn, (const half8*)Wp, dcb, dcnT);
    k_finalm   <<<NSP / 64, 256, 0, stream>>>(dcnT, Uh, x, (const half8*)Wc1, c1b,
                                              (const half8*)Wp2f, p2b, out);
}

// Round 17
// 120.011 us; speedup vs baseline: 1.2111x; 1.2111x over previous
//
#include <hip/hip_runtime.h>
#include <math.h>

#define NSP 32768   // H*W*D = 32*32*32
#define NCH 64

typedef _Float16 half8 __attribute__((ext_vector_type(8)));
typedef _Float16 half4 __attribute__((ext_vector_type(4)));
typedef _Float16 half2v __attribute__((ext_vector_type(2)));
typedef float f32x4 __attribute__((ext_vector_type(4)));

// ---------------------------------------------------------------------------
// K1 (MFMA): U = gelu(proj1_w @ x^T + b)   (U layout: f16 [C][N])
__global__ __launch_bounds__(256) void k_proj1m(const float* __restrict__ x,
        const half8* __restrict__ Wp1, const float* __restrict__ b,
        _Float16* __restrict__ Uh) {
    __shared__ __align__(16) _Float16 Sx[64 * 72];   // 9216 B
    int t = threadIdx.x;
    int n0 = blockIdx.x * 64;
    int lane = t & 63, wv = t >> 6;
    for (int i = wv; i < 64; i += 4) {
        float v = x[(size_t)(n0 + i) * 64 + lane];
        Sx[i * 72 + lane] = (_Float16)v;
    }
    __syncthreads();
    int pl = lane & 15, g = lane >> 4;
    int ob = wv;
    const half8* wbase = Wp1 + ob * 64 + lane;       // +256 per kb
    #pragma unroll
    for (int nt = 0; nt < 4; ++nt) {
        f32x4 acc4 = {0.f, 0.f, 0.f, 0.f};
        const _Float16* sb = &Sx[(nt * 16 + pl) * 72 + g * 8];
        #pragma unroll
        for (int kb = 0; kb < 2; ++kb) {
            half8 af = wbase[kb * 256];
            half8 bf = *(const half8*)(sb + kb * 32);
            acc4 = __builtin_amdgcn_mfma_f32_16x16x32_f16(af, bf, acc4, 0, 0, 0);
        }
        int n = n0 + nt * 16 + pl;
        #pragma unroll
        for (int r = 0; r < 4; ++r) {
            int o = ob * 16 + g * 4 + r;
            float a = acc4[r] + b[o];
            float gv = 0.5f * a * (1.0f + erff(a * 0.70710678118654752f));
            Uh[(size_t)o * NSP + n] = (_Float16)gv;
        }
    }
}

// ---------------------------------------------------------------------------
// K2: depthwise 5x5x5, pad 2.  f16 in/out; weights uniform->SGPR.
__global__ __launch_bounds__(256) void k_dw5(const _Float16* __restrict__ in,
        const float* __restrict__ w, const float* __restrict__ b,
        _Float16* __restrict__ out) {
    __shared__ float Sb5[2][20 * 38];                // 6080 B
    int t = threadIdx.x;
    int bid = blockIdx.x;
    int blk = (bid & 7) * 128 + (bid >> 3);          // XCD-chunked
    int c  = blk >> 4;
    int hq = (blk >> 1) & 7;
    int wq = blk & 1;
    int d  = t & 31;
    int wbloc = t >> 5;                              // 0..7
    int wb = wq * 8 + wbloc;
    const float* wc = w + c * 125;                   // uniform -> scalar loads
    const _Float16* src = in + ((size_t)c << 15);

    for (int idx = t; idx < 160; idx += 256) {
        int bi = idx / 80, r = idx % 80;
        int wi = r >> 2, e = r & 3;
        int Dp = (e < 2) ? e : 32 + e;               // {0,1,34,35}
        Sb5[bi][wi * 38 + Dp] = 0.f;
    }

    float bc = b[c];
    float acc[4][2];
    #pragma unroll
    for (int a = 0; a < 4; ++a) { acc[a][0] = bc; acc[a][1] = bc; }

    #define STAGE5(m)                                                        \
        { int hh_ = 4 * hq + (m) - 2;                                        \
          if ((unsigned)hh_ < 32u) {                                         \
            const _Float16* row_ = src + (hh_ << 10);                        \
            for (int idx = t; idx < 80; idx += 256) {                        \
                int wi = idx >> 2, oct = idx & 3;                            \
                int wj = 16 * wq - 2 + wi;                                   \
                half8 vv = (half8)(_Float16)0.f;                             \
                if ((unsigned)wj < 32u)                                      \
                    vv = *(const half8*)&row_[(wj << 5) + oct * 8];          \
                float* dst = &Sb5[(m) & 1][wi * 38 + 2 + oct * 8];           \
                dst[0] = (float)vv[0]; dst[1] = (float)vv[1];                \
                dst[2] = (float)vv[2]; dst[3] = (float)vv[3];                \
                dst[4] = (float)vv[4]; dst[5] = (float)vv[5];                \
                dst[6] = (float)vv[6]; dst[7] = (float)vv[7];                \
            } } }

    STAGE5(0)
    __syncthreads();
    #pragma unroll 1
    for (int m = 0; m < 8; ++m) {
        if (m < 7) STAGE5(m + 1)
        int hh = 4 * hq + m - 2;
        if ((unsigned)hh < 32u) {
            float v[6][5];
            const float* sb = &Sb5[m & 1][0];
            #pragma unroll
            for (int jc = 0; jc < 6; ++jc)
                #pragma unroll
                for (int l = 0; l < 5; ++l)
                    v[jc][l] = sb[(2 * wbloc + jc) * 38 + d + l];
            #pragma unroll
            for (int a = 0; a < 4; ++a) {
                if (a <= m && m <= a + 4) {
                    const float* wr = wc + (m - a) * 25;   // uniform
                    float s0 = 0.f, s1 = 0.f;
                    #pragma unroll
                    for (int j = 0; j < 5; ++j)
                        #pragma unroll
                        for (int l = 0; l < 5; ++l) {
                            float wv2 = wr[j * 5 + l];
                            s0 += wv2 * v[j][l];
                            s1 += wv2 * v[j + 1][l];
                        }
                    acc[a][0] += s0;
                    acc[a][1] += s1;
                }
            }
        }
        __syncthreads();
    }
    #pragma unroll
    for (int a = 0; a < 4; ++a)
        #pragma unroll
        for (int bb = 0; bb < 2; ++bb)
            out[(size_t)c * NSP + ((4 * hq + a) << 10) + ((2 * wb + bb) << 5) + d]
                = (_Float16)acc[a][bb];
    #undef STAGE5
}

// ---------------------------------------------------------------------------
// K3: depthwise 7x7x7 dilation 3.  f16 in/out; half8 staging; pk inner.
__global__ __launch_bounds__(256) void k_dw7(const _Float16* __restrict__ in,
        const float* __restrict__ w, const float* __restrict__ b,
        _Float16* __restrict__ out) {
    __shared__ float Sb7[2][26 * 52];                // 10816 B
    int t = threadIdx.x;
    int bid = blockIdx.x;
    int blk = (bid & 7) * 96 + (bid >> 3);           // XCD-chunked
    int c  = blk / 12;
    int h0 = (blk % 12) >> 2;
    int wq = blk & 3;
    int d  = t & 31;
    int wloc = t >> 5;                               // 0..7
    int w_ = wq * 8 + wloc;
    const float* wc = w + c * 343;                   // uniform -> scalar loads
    const _Float16* src = in + ((size_t)c << 15);

    for (int idx = t; idx < 936; idx += 256) {
        int bi = idx / 468, r = idx % 468;
        int wi = r / 18, e = r % 18;
        int Dp = (e < 9) ? e : 32 + e;               // {0..8, 41..49}
        Sb7[bi][wi * 52 + Dp] = 0.f;
    }

    float bc = b[c];
    float acc[11];
    #pragma unroll
    for (int a = 0; a < 11; ++a) acc[a] = bc;

    #define STAGE7(m)                                                        \
        { int hh_ = h0 + 3 * (m) - 9;                                        \
          if ((unsigned)hh_ < 32u) {                                         \
            const _Float16* row_ = src + (hh_ << 10);                        \
            for (int idx = t; idx < 104; idx += 256) {                       \
                int wi = idx >> 2, oct = idx & 3;                            \
                int wj = 8 * wq - 9 + wi;                                    \
                half8 vv = (half8)(_Float16)0.f;                             \
                if ((unsigned)wj < 32u)                                      \
                    vv = *(const half8*)&row_[(wj << 5) + oct * 8];          \
                float* dst = &Sb7[(m) & 1][wi * 52 + 9 + oct * 8];           \
                dst[0] = (float)vv[0]; dst[1] = (float)vv[1];                \
                dst[2] = (float)vv[2]; dst[3] = (float)vv[3];                \
                dst[4] = (float)vv[4]; dst[5] = (float)vv[5];                \
                dst[6] = (float)vv[6]; dst[7] = (float)vv[7];                \
            } } }

    STAGE7(0)
    __syncthreads();
    #pragma unroll 1
    for (int m = 0; m < 17; ++m) {
        if (m < 16) STAGE7(m + 1)
        int hh = h0 + 3 * m - 9;
        if ((unsigned)hh < 32u) {
            float vf[49];
            const float* sb = &Sb7[m & 1][0];
            #pragma unroll
            for (int jw = 0; jw < 7; ++jw)
                #pragma unroll
                for (int l = 0; l < 7; ++l)
                    vf[jw * 7 + l] = sb[(wloc + 3 * jw) * 52 + d + 3 * l];
            #pragma unroll
            for (int a = 0; a < 11; ++a) {
                if (a <= m && m <= a + 6) {
                    const float* wr = wc + (m - a) * 49;   // uniform
                    float sA = 0.f, sB = 0.f;              // 2 chains -> pk
                    #pragma unroll
                    for (int q = 0; q < 24; ++q) {
                        sA = fmaf(wr[2 * q],     vf[2 * q],     sA);
                        sB = fmaf(wr[2 * q + 1], vf[2 * q + 1], sB);
                    }
                    acc[a] += sA + sB + wr[48] * vf[48];
                }
            }
        }
        __syncthreads();
    }
    #pragma unroll
    for (int a = 0; a < 11; ++a) {
        int h = h0 + 3 * a;
        if (h < 32)
            out[(size_t)c * NSP + (h << 10) + (w_ << 5) + d] = (_Float16)acc[a];
    }
    #undef STAGE7
}

// ---------------------------------------------------------------------------
// K4: transpose f16 [C][N] -> f16 [N][C], half8 both sides
__global__ __launch_bounds__(256) void k_tr(const _Float16* __restrict__ in,
        _Float16* __restrict__ outh) {
    __shared__ __align__(16) _Float16 tile[64 * 74];  // 9472 B
    int t = threadIdx.x;
    int n0 = blockIdx.x * 64;
    #pragma unroll
    for (int i = 0; i < 2; ++i) {
        int u = i * 256 + t;         // 0..511
        int c = u >> 3, oct = u & 7;
        half8 v = *(const half8*)&in[(size_t)c * NSP + n0 + oct * 8];
        *(half8*)&tile[c * 74 + oct * 8] = v;
    }
    __syncthreads();
    #pragma unroll
    for (int i = 0; i < 2; ++i) {
        int u = i * 256 + t;
        int nl = u >> 3, co = u & 7;
        half8 r;
        #pragma unroll
        for (int j = 0; j < 8; ++j) r[j] = tile[(co * 8 + j) * 74 + nl];
        *(half8*)&outh[(size_t)(n0 + nl) * 64 + co * 8] = r;
    }
}

// ---------------------------------------------------------------------------
// K5 (fused): ALL weight packs in one kernel.
__global__ __launch_bounds__(256) void k_wpack_all(
        const float* __restrict__ p1w, const float* __restrict__ c1w,
        const float* __restrict__ p2w, const float* __restrict__ dcw,
        const float* __restrict__ ofw,
        _Float16* __restrict__ Wp1, _Float16* __restrict__ Wc1,
        _Float16* __restrict__ Wp2f, _Float16* __restrict__ Wp,
        _Float16* __restrict__ Wp2) {
    int bidx = blockIdx.x;
    int t = threadIdx.x;
    if (bidx < 48) {
        const float* w = (bidx < 16) ? p1w : (bidx < 32) ? c1w : p2w;
        _Float16* Wd   = (bidx < 16) ? Wp1 : (bidx < 32) ? Wc1 : Wp2f;
        int idx = (bidx & 15) * 256 + t;             // 0..4095
        int j = idx & 7;
        int l = (idx >> 3) & 63;
        int obk = idx >> 9;
        int ob = obk & 3, kb = obk >> 2;
        int o = ob * 16 + (l & 15);
        int Kp = kb * 32 + (l >> 4) * 8 + j;
        Wd[idx] = (_Float16)w[o * 64 + Kp];
    } else if (bidx < 480) {
        int idx = (bidx - 48) * 256 + t;             // 0..110591
        int j = idx & 7;
        int l = (idx >> 3) & 63;
        int obk = idx >> 9;
        int ob = obk & 3, kb = obk >> 2;
        int o = ob * 16 + (l & 15);
        int Kp = kb * 32 + (l >> 4) * 8 + j;
        int k = Kp >> 6, c = Kp & 63;
        Wp[idx] = (_Float16)dcw[(size_t)o * 1728 + c * 27 + k];
    } else {
        int idx = (bidx - 480) * 256 + t;            // 0..165887
        int j = idx & 7;
        int l = (idx >> 3) & 63;
        int obk = idx >> 9;                          // 0..323
        int ob = obk % 6, kb = obk / 6;
        int o = ob * 16 + (l & 15);
        int Kp = kb * 32 + (l >> 4) * 8 + j;
        int k = Kp >> 6, c = Kp & 63;
        Wp2[idx] = (o < 81) ? (_Float16)ofw[(size_t)o * 1728 + c * 27 + k]
                            : (_Float16)0.f;
    }
}

// ---------------------------------------------------------------------------
// K5c: offset conv, 32-position tile, kh-chunked dbuf halo.  Output OFFn f16
// [N][108] (slot = k*4 + comp) via LDS-transpose epilogue (aliased).
__global__ __launch_bounds__(384) void k_offg(const _Float16* __restrict__ aTh,
        const half8* __restrict__ Wp2, const float* __restrict__ obias,
        _Float16* __restrict__ OFFn) {
    __shared__ __align__(16) char SMEM[29376];       // S2 | TFh alias
    _Float16* S2  = (_Float16*)SMEM;                 // [2][3*34*72]
    _Float16* TFh = (_Float16*)SMEM;                 // [32][108]
    const int SB = 3 * 34 * 72;                      // 7344 halfs per buffer
    int t = threadIdx.x;
    int bid = blockIdx.x;
    int blk = (bid & 7) * 128 + (bid >> 3);          // 1024 blocks, XCD-chunked
    int h = blk >> 5, w = blk & 31;
    int n0 = blk << 5;
    int lane = t & 63, wv = t >> 6;                  // wv 0..5
    int co8 = (lane & 7) << 3;

    for (int u = t; u < 864; u += 384) {             // zero d-edge rows
        int bi = u / 432, r2 = u % 432;
        int nbw = r2 / 144, r3 = r2 % 144;
        int dd = (r3 >= 72) ? 33 : 0, cc = r3 % 72;
        S2[bi * SB + (nbw * 34 + dd) * 72 + cc] = (_Float16)0.f;
    }

    int pl = lane & 15, g = lane >> 4;
    int obi = wv;
    f32x4 acc[2];
    acc[0] = (f32x4){0.f, 0.f, 0.f, 0.f};
    acc[1] = (f32x4){0.f, 0.f, 0.f, 0.f};
    const half8* wb = Wp2 + obi * 64 + lane;

    #define OSTAGE(kh)                                                        \
        { int hh_ = h + (kh) - 1;                                            \
          bool okh_ = (unsigned)hh_ < 32u;                                   \
          for (int u = wv; u < 12; u += 6) {                                 \
              int nbw = u >> 2, oct = u & 3;                                 \
              int wj = w + nbw - 1;                                          \
              int di = oct * 8 + (lane >> 3);                                \
              bool ok = okh_ & ((unsigned)wj < 32u);                         \
              half8 vv = (half8)(_Float16)0.f;                               \
              if (ok) vv = *(const half8*)(aTh +                             \
                  ((size_t)((((hh_ << 5) + wj) << 5) + di)) * 64 + co8);     \
              *(half8*)&S2[((kh) & 1) * SB + (nbw * 34 + 1 + di) * 72 + co8] \
                  = vv;                                                      \
          } }

    #define OCOMP(kh)                                                        \
        { const _Float16* sb = &S2[((kh) & 1) * SB + pl * 72 + g * 8];       \
          _Pragma("unroll")                                                  \
          for (int kk = 0; kk < 18; ++kk) {                                  \
              int kglob = (kh) * 9 + (kk >> 1);                              \
              int kw3 = (kglob / 3) % 3, kd = kglob % 3;                     \
              half8 af = wb[(size_t)((kh) * 18 + kk) * 384];                 \
              _Pragma("unroll")                                              \
              for (int pt = 0; pt < 2; ++pt) {                               \
                  int row = kw3 * 34 + pt * 16 + kd;                         \
                  half8 bf = *(const half8*)(sb + row * 72 + (kk & 1) * 32); \
                  acc[pt] = __builtin_amdgcn_mfma_f32_16x16x32_f16(          \
                                af, bf, acc[pt], 0, 0, 0);                   \
              }                                                              \
          } }

    OSTAGE(0)
    __syncthreads();
    OSTAGE(1)
    OCOMP(0)
    __syncthreads();
    OSTAGE(2)
    OCOMP(1)
    __syncthreads();
    OCOMP(2)
    #undef OSTAGE
    #undef OCOMP

    __syncthreads();                                 // S2 -> TFh alias switch
    #pragma unroll
    for (int pt = 0; pt < 2; ++pt) {
        int pos = pt * 16 + pl;
        #pragma unroll
        for (int r = 0; r < 4; ++r) {
            int o = obi * 16 + g * 4 + r;
            if (o < 81) {
                int slot = (o / 3) * 4 + o % 3;
                TFh[pos * 108 + slot] = (_Float16)(acc[pt][r] + obias[o]);
            }
        }
    }
    __syncthreads();
    for (int u = t; u < 864; u += 384) {             // 32 rows x 27 half4
        int row = u / 27, q = u - row * 27;
        half4 v = *(const half4*)&TFh[row * 108 + q * 4];
        *(half4*)&OFFn[(size_t)(n0 + row) * 108 + q * 4] = v;
    }
}

// ---------------------------------------------------------------------------
// K6: deformable gather + MFMA GEMM, 32-position blocks, 6 K-chunks of <=5
// taps (S 21 KB; total LDS 31.4 KB).  OFFn f16 reads.  Global scattered
// gather (proven optimal vs LDS-halo: R16 regression, bank-conflict-bound).
__global__ __launch_bounds__(256) void k_deform(const _Float16* __restrict__ aTh,
        const _Float16* __restrict__ OFFn, const half8* __restrict__ Wp,
        const float* __restrict__ db, _Float16* __restrict__ dcnT) {
    __shared__ __align__(16) _Float16 S[32 * 328];     // 20992 B (5 taps max)
    __shared__ __align__(16) _Float16 TPF[864 * 4];    // 6912 B {rh,rw,rd,_}
    __shared__ int TPv[864];                           // 1728*2 B (total 31360)
    int t = threadIdx.x;
    int bid = blockIdx.x;
    int blk = (bid & 7) * 128 + (bid >> 3);  // 1024 blocks, n-slabs per XCD
    int n0 = blk * 32;
    int lane = t & 63, wv = t >> 6;

    for (int idx = t; idx < 864; idx += 256) {        // Phase A: 27k x 32p
        int p = idx & 31, k = idx >> 5;
        int n = n0 + p;
        int h = n >> 10, w = (n >> 5) & 31, d = n & 31;
        half4 ov4 = *(const half4*)&OFFn[(size_t)n * 108 + k * 4];
        float ph = (float)(h + k / 9 - 1)       + (float)ov4[0];
        float pw = (float)(w + (k / 3) % 3 - 1) + (float)ov4[1];
        float pd = (float)(d + k % 3 - 1)       + (float)ov4[2];
        float fh = floorf(ph), fw = floorf(pw), fd = floorf(pd);
        int ih = (int)fh, iw = (int)fw, id = (int)fd;
        int nb0 = ih * 1024 + iw * 32 + id;
        int mask = 0;
        #pragma unroll
        for (int cb = 0; cb < 8; ++cb) {
            int hh = ih + ((cb >> 2) & 1);
            int wq = iw + ((cb >> 1) & 1);
            int dq = id + (cb & 1);
            bool ok = ((unsigned)hh < 32u) & ((unsigned)wq < 32u) & ((unsigned)dq < 32u);
            mask |= (ok ? 1 : 0) << cb;
        }
        TPv[idx] = ((nb0 + 4096) << 8) | mask;
        half4 f;
        f[0] = (_Float16)(ph - fh);
        f[1] = (_Float16)(pw - fw);
        f[2] = (_Float16)(pd - fd);
        f[3] = (_Float16)0.f;
        *(half4*)&TPF[idx * 4] = f;
    }
    __syncthreads();

    int p8 = lane >> 3, co = lane & 7;
    int pl = lane & 15, g = lane >> 4;
    f32x4 acc[2];
    acc[0] = (f32x4){0.f, 0.f, 0.f, 0.f};
    acc[1] = (f32x4){0.f, 0.f, 0.f, 0.f};
    const half8* wbase = Wp + wv * 64 + lane;
    const _Float16* sbase0 = &S[pl * 328 + g * 8];
    const _Float16* sbase1 = &S[(16 + pl) * 328 + g * 8];

    #define DCHUNK(T0, NT)                                                   \
        for (int u = wv; u < (NT) * 4; u += 4) {                             \
            int kk = u >> 2, pg = u & 3;                                     \
            int p = pg * 8 + p8;                                             \
            int tap = ((T0) + kk) * 32 + p;                                  \
            int v = TPv[tap];                                                \
            int nb = (v >> 8) - 4096, mask = v & 255;                        \
            int snb = nb < 0 ? 0 : (nb > 32767 ? 32767 : nb);                \
            half4 f = *(const half4*)&TPF[tap * 4];                          \
            _Float16 one = (_Float16)1.f;                                    \
            _Float16 rh = f[0], rw = f[1], rd = f[2];                        \
            _Float16 h0 = one - rh, w0 = one - rw, d0 = one - rd;            \
            _Float16 t00 = h0 * w0, t01 = h0 * rw;                           \
            _Float16 t10 = rh * w0, t11 = rh * rw;                           \
            half2v a0 = (half2v)0, a1 = (half2v)0, a2 = (half2v)0,           \
                   a3 = (half2v)0;                                           \
            _Pragma("unroll")                                                \
            for (int i = 0; i < 8; ++i) {                                    \
                int nn = nb + ((i >> 2) & 1) * 1024 + ((i >> 1) & 1) * 32    \
                       + (i & 1);                                            \
                bool okc = (mask >> i) & 1;                                  \
                size_t ad = (size_t)(okc ? nn : snb) << 6;                   \
                half8 vv = *(const half8*)(aTh + ad + (co << 3));            \
                _Float16 txy = (i & 4) ? ((i & 2) ? t11 : t10)               \
                                       : ((i & 2) ? t01 : t00);              \
                _Float16 wg = txy * ((i & 1) ? rd : d0);                     \
                wg = okc ? wg : (_Float16)0.f;                               \
                half2v wg2 = {wg, wg};                                       \
                a0 += (half2v){vv[0], vv[1]} * wg2;                          \
                a1 += (half2v){vv[2], vv[3]} * wg2;                          \
                a2 += (half2v){vv[4], vv[5]} * wg2;                          \
                a3 += (half2v){vv[6], vv[7]} * wg2;                          \
            }                                                                \
            half8 r;                                                         \
            r[0] = a0[0]; r[1] = a0[1]; r[2] = a1[0]; r[3] = a1[1];          \
            r[4] = a2[0]; r[5] = a2[1]; r[6] = a3[0]; r[7] = a3[1];          \
            *(half8*)&S[p * 328 + kk * 64 + (co << 3)] = r;                  \
        }                                                                    \
        __syncthreads();                                                     \
        _Pragma("unroll")                                                    \
        for (int kb = 0; kb < (NT) * 2; ++kb) {                              \
            half8 af = wbase[(size_t)(2 * (T0) + kb) * 256];                 \
            half8 bf0 = *(const half8*)(sbase0 + kb * 32);                   \
            half8 bf1 = *(const half8*)(sbase1 + kb * 32);                   \
            acc[0] = __builtin_amdgcn_mfma_f32_16x16x32_f16(af, bf0,         \
                         acc[0], 0, 0, 0);                                   \
            acc[1] = __builtin_amdgcn_mfma_f32_16x16x32_f16(af, bf1,         \
                         acc[1], 0, 0, 0);                                   \
        }                                                                    \
        __syncthreads();

    DCHUNK(0, 5)
    DCHUNK(5, 5)
    DCHUNK(10, 5)
    DCHUNK(15, 5)
    DCHUNK(20, 5)
    DCHUNK(25, 2)
    #undef DCHUNK

    #pragma unroll
    for (int pt = 0; pt < 2; ++pt) {
        half4 hv;
        #pragma unroll
        for (int r2 = 0; r2 < 4; ++r2) {
            int o = wv * 16 + g * 4 + r2;
            hv[r2] = (_Float16)(acc[pt][r2] + db[o]);
        }
        *(half4*)&dcnT[(size_t)(n0 + pt * 16 + pl) * 64 + wv * 16 + g * 4] = hv;
    }
}

// ---------------------------------------------------------------------------
// K7 (MFMA): a2 = conv1_w @ dcn + b ; h = U * a2 ; out = proj2_w @ h + b2 + x
__global__ __launch_bounds__(256) void k_finalm(const _Float16* __restrict__ dcnT,
        const _Float16* __restrict__ Uh, const float* __restrict__ x,
        const half8* __restrict__ Wc1, const float* __restrict__ c1b,
        const half8* __restrict__ Wp2f, const float* __restrict__ p2b,
        float* __restrict__ out) {
    __shared__ __align__(16) _Float16 Sd[64 * 72];   // 9216 B
    __shared__ __align__(16) _Float16 Sh[64 * 72];   // 9216 B
    int t = threadIdx.x;
    int n0 = blockIdx.x * 64;
    int lane = t & 63, wv = t >> 6;
    #pragma unroll
    for (int i = 0; i < 2; ++i) {
        int u = i * 256 + t;
        int nl = u >> 3, oct = u & 7;
        *(half8*)&Sd[nl * 72 + oct * 8] =
            *(const half8*)&dcnT[(size_t)(n0 + nl) * 64 + oct * 8];
    }
    __syncthreads();

    int pl = lane & 15, g = lane >> 4;
    int ob = wv;
    const half8* w1 = Wc1 + ob * 64 + lane;
    #pragma unroll
    for (int nt = 0; nt < 4; ++nt) {                 // GEMM1 + gate
        f32x4 acc4 = {0.f, 0.f, 0.f, 0.f};
        const _Float16* sb = &Sd[(nt * 16 + pl) * 72 + g * 8];
        #pragma unroll
        for (int kb = 0; kb < 2; ++kb) {
            half8 af = w1[kb * 256];
            half8 bf = *(const half8*)(sb + kb * 32);
            acc4 = __builtin_amdgcn_mfma_f32_16x16x32_f16(af, bf, acc4, 0, 0, 0);
        }
        int n = n0 + nt * 16 + pl;
        int o0 = ob * 16 + g * 4;
        float4 bb = *(const float4*)&c1b[o0];
        half4 hv;
        hv[0] = (_Float16)((float)Uh[(size_t)(o0 + 0) * NSP + n] * (acc4[0] + bb.x));
        hv[1] = (_Float16)((float)Uh[(size_t)(o0 + 1) * NSP + n] * (acc4[1] + bb.y));
        hv[2] = (_Float16)((float)Uh[(size_t)(o0 + 2) * NSP + n] * (acc4[2] + bb.z));
        hv[3] = (_Float16)((float)Uh[(size_t)(o0 + 3) * NSP + n] * (acc4[3] + bb.w));
        *(half4*)&Sh[(nt * 16 + pl) * 72 + o0] = hv;
    }
    __syncthreads();

    const half8* w2 = Wp2f + ob * 64 + lane;
    #pragma unroll
    for (int nt = 0; nt < 4; ++nt) {                 // GEMM2 + residual
        f32x4 acc4 = {0.f, 0.f, 0.f, 0.f};
        const _Float16* sb = &Sh[(nt * 16 + pl) * 72 + g * 8];
        #pragma unroll
        for (int kb = 0; kb < 2; ++kb) {
            half8 af = w2[kb * 256];
            half8 bf = *(const half8*)(sb + kb * 32);
            acc4 = __builtin_amdgcn_mfma_f32_16x16x32_f16(af, bf, acc4, 0, 0, 0);
        }
        int n = n0 + nt * 16 + pl;
        int o0 = ob * 16 + g * 4;
        float4 bb = *(const float4*)&p2b[o0];
        float4 xr = *(const float4*)&x[(size_t)n * 64 + o0];
        float4 ov;
        ov.x = acc4[0] + bb.x + xr.x;
        ov.y = acc4[1] + bb.y + xr.y;
        ov.z = acc4[2] + bb.z + xr.z;
        ov.w = acc4[3] + bb.w + xr.w;
        *(float4*)&out[(size_t)n * 64 + o0] = ov;
    }
}

// ---------------------------------------------------------------------------
extern "C" void kernel_launch(void* const* d_in, const int* in_sizes, int n_in,
                              void* d_out, int out_size, void* d_ws, size_t ws_size,
                              hipStream_t stream) {
    const float* x   = (const float*)d_in[0];
    const float* p1w = (const float*)d_in[1];
    const float* p1b = (const float*)d_in[2];
    const float* c0w = (const float*)d_in[3];
    const float* c0b = (const float*)d_in[4];
    const float* csw = (const float*)d_in[5];
    const float* csb = (const float*)d_in[6];
    const float* ofw = (const float*)d_in[7];
    const float* ofb = (const float*)d_in[8];
    const float* dcw = (const float*)d_in[9];
    const float* dcb = (const float*)d_in[10];
    const float* c1w = (const float*)d_in[11];
    const float* c1b = (const float*)d_in[12];
    const float* p2w = (const float*)d_in[13];
    const float* p2b = (const float*)d_in[14];
    float* out = (float*)d_out;

    char* ws = (char*)d_ws;
    const size_t CN2 = (size_t)NCH * NSP * 2;       // 4 MiB per [C][N] f16
    _Float16* Uh   = (_Float16*)(ws);
    _Float16* T0h  = (_Float16*)(ws + CN2);
    _Float16* T1h  = (_Float16*)(ws + 2 * CN2);
    _Float16* aTh  = (_Float16*)(ws + 3 * CN2);
    _Float16* OFFn = (_Float16*)(ws + 4 * CN2);     // [N][108] f16 = 7.08 MB
    _Float16* dcnT = (_Float16*)(ws + 4 * CN2 + (size_t)NSP * 108 * 2);
    _Float16* Wp   = dcnT + (size_t)NSP * 64;
    _Float16* Wp2  = Wp + 110592;
    _Float16* Wp1  = Wp2 + 165888;
    _Float16* Wc1  = Wp1 + 4096;
    _Float16* Wp2f = Wc1 + 4096;

    k_wpack_all<<<1128, 256, 0, stream>>>(p1w, c1w, p2w, dcw, ofw,
                                          Wp1, Wc1, Wp2f, Wp, Wp2);
    k_proj1m   <<<NSP / 64, 256, 0, stream>>>(x, (const half8*)Wp1, p1b, Uh);
    k_dw5      <<<1024, 256, 0, stream>>>(Uh, c0w, c0b, T0h);
    k_dw7      <<<768, 256, 0, stream>>>(T0h, csw, csb, T1h);
    k_tr       <<<NSP / 64, 256, 0, stream>>>(T1h, aTh);
    k_offg     <<<1024, 384, 0, stream>>>(aTh, (const half8*)Wp2, ofb, OFFn);
    k_deform   <<<1024, 256, 0, stream>>>(aTh, OFFn, (const half8*)Wp, dcb, dcnT);
    k_finalm   <<<NSP / 64, 256, 0, stream>>>(dcnT, Uh, x, (const half8*)Wc1, c1b,
                                              (const half8*)Wp2f, p2b, out);
}